// Round 4
// baseline (282.139 us; speedup 1.0000x reference)
//
#include <hip/hip_runtime.h>

typedef unsigned short u16;
typedef unsigned int u32;
typedef __bf16 bf16x8 __attribute__((ext_vector_type(8)));
typedef float f32x4 __attribute__((ext_vector_type(4)));

#define DEV __device__ __forceinline__

// Problem constants (B,T,D_MODEL,H) = (2,2048,1024,16)
constexpr int BB = 2;
constexpr int TT = 2048;
constexpr int CD = 1024;
constexpr int HH = 16;
constexpr int DH = 64;
constexpr int BT = BB * TT;   // 4096

DEV u16 f2bf(float f) {
    u32 u = __builtin_bit_cast(u32, f);
    u32 r = u + 0x7FFFu + ((u >> 16) & 1u);
    return (u16)(r >> 16);
}

// ---------------------------------------------------------------------------
// Elementwise fp32 -> bf16 convert. n must be a multiple of 2048*8.
// ---------------------------------------------------------------------------
__global__ __launch_bounds__(256)
void convert_f32_bf16(const float* __restrict__ in, u16* __restrict__ out, int n) {
    const int i = (blockIdx.x * 256 + threadIdx.x) * 8;
    if (i >= n) return;
    float4 a = *(const float4*)&in[i];
    float4 b = *(const float4*)&in[i + 4];
    u16 t[8];
    t[0] = f2bf(a.x); t[1] = f2bf(a.y); t[2] = f2bf(a.z); t[3] = f2bf(a.w);
    t[4] = f2bf(b.x); t[5] = f2bf(b.y); t[6] = f2bf(b.z); t[7] = f2bf(b.w);
    *(uint4*)&out[i] = *(const uint4*)t;
}

// ---------------------------------------------------------------------------
// Fused transpose + fp32->bf16: out[c][r] = bf16(in[r][c]).
// rows, cols multiples of 32. Grid (cols/32, rows/32), block (32,8).
// ---------------------------------------------------------------------------
__global__ __launch_bounds__(256)
void transpose_f32_bf16(const float* __restrict__ in, u16* __restrict__ out,
                        int rows, int cols) {
    __shared__ u16 tile[32][33];
    const int c0 = blockIdx.x * 32, r0 = blockIdx.y * 32;
    const int tx = threadIdx.x, ty = threadIdx.y;
    #pragma unroll
    for (int i = ty; i < 32; i += 8)
        tile[i][tx] = f2bf(in[(r0 + i) * cols + (c0 + tx)]);
    __syncthreads();
    #pragma unroll
    for (int i = ty; i < 32; i += 8)
        out[(c0 + i) * rows + (r0 + tx)] = tile[tx][i];
}

// ---------------------------------------------------------------------------
// GEMM: C[M][N] = A[M][K] * Bt[N][K]^T,  bf16 in, fp32 acc.
// 128x128 block tile, BK=32, 4 waves each computing 64x64 (4x4 MFMA tiles).
// EPI==0: plain store to outf (fp32, row-major MxN)  <-- final output dtype
// EPI==1: QKV scatter: q,k -> (B,H,T,64) bf16; v -> (B,H,64,T) bf16 (V^T).
// ---------------------------------------------------------------------------
template <int EPI>
__global__ __launch_bounds__(256)
void gemm_bt(const u16* __restrict__ A, const u16* __restrict__ Bt,
             u16* __restrict__ out0, u16* __restrict__ out1,
             u16* __restrict__ out2, float* __restrict__ outf,
             int M, int N, int K) {
    constexpr int BM = 128, BN = 128, BK = 32;
    constexpr int AST = 40;  // padded LDS row stride (elements)
    __shared__ alignas(16) u16 As[BM * AST];
    __shared__ alignas(16) u16 Bs[BN * AST];

    const int tid  = threadIdx.x;
    const int wave = tid >> 6, lane = tid & 63;
    const int quad = lane >> 4, l16 = lane & 15;
    const int wm = (wave & 1) * 64, wn = (wave >> 1) * 64;
    const int m0 = blockIdx.y * BM, n0 = blockIdx.x * BN;
    const int ar = tid >> 2;          // staging row 0..63 (and +64)
    const int ak = (tid & 3) * 8;     // staging k-offset (elements)

    f32x4 acc[4][4] = {};

    for (int k0 = 0; k0 < K; k0 += BK) {
        *(uint4*)&As[ar * AST + ak]        = *(const uint4*)&A[(m0 + ar) * K + k0 + ak];
        *(uint4*)&As[(ar + 64) * AST + ak] = *(const uint4*)&A[(m0 + ar + 64) * K + k0 + ak];
        *(uint4*)&Bs[ar * AST + ak]        = *(const uint4*)&Bt[(n0 + ar) * K + k0 + ak];
        *(uint4*)&Bs[(ar + 64) * AST + ak] = *(const uint4*)&Bt[(n0 + ar + 64) * K + k0 + ak];
        __syncthreads();

        bf16x8 fa[4], fb[4];
        #pragma unroll
        for (int mt = 0; mt < 4; ++mt)
            fa[mt] = *(const bf16x8*)&As[(wm + mt * 16 + l16) * AST + quad * 8];
        #pragma unroll
        for (int nt = 0; nt < 4; ++nt)
            fb[nt] = *(const bf16x8*)&Bs[(wn + nt * 16 + l16) * AST + quad * 8];
        #pragma unroll
        for (int mt = 0; mt < 4; ++mt)
            #pragma unroll
            for (int nt = 0; nt < 4; ++nt)
                acc[mt][nt] = __builtin_amdgcn_mfma_f32_16x16x32_bf16(
                    fa[mt], fb[nt], acc[mt][nt], 0, 0, 0);
        __syncthreads();
    }

    // Epilogue. C/D layout: row = quad*4+reg, col = l16 (m89/m91-verified).
    #pragma unroll
    for (int mt = 0; mt < 4; ++mt) {
        #pragma unroll
        for (int nt = 0; nt < 4; ++nt) {
            #pragma unroll
            for (int reg = 0; reg < 4; ++reg) {
                const int r = m0 + wm + mt * 16 + quad * 4 + reg;  // row in M
                const int c = n0 + wn + nt * 16 + l16;             // col in N
                if (EPI == 0) {
                    outf[r * N + c] = acc[mt][nt][reg];            // fp32 out
                } else {
                    const u16 v = f2bf(acc[mt][nt][reg]);
                    const int which = c >> 10;       // 0=q 1=k 2=v
                    const int cc = c & 1023;
                    const int h = cc >> 6, d = cc & 63;
                    const int b = r >> 11, t = r & 2047;
                    const int bh = b * HH + h;
                    if (which == 0)      out0[(bh * TT + t) * DH + d] = v;
                    else if (which == 1) out1[(bh * TT + t) * DH + d] = v;
                    else                 out2[(bh * DH + d) * TT + t] = v;
                }
            }
        }
    }
}

// ---------------------------------------------------------------------------
// Flash attention (causal).  Grid: (T/64, B*H).  Block: 256 = 4 waves.
// Each wave owns 16 q-rows; K-tile (64x64, [key][d]) and V^T-tile
// (64x64, [d][key]) staged in LDS (row stride 72 elems = 144 B: bank step 4,
// conflict-free b128 reads); P round-trips through per-wave LDS to go from
// C-layout (q=quad*4+reg, key=l16) to A-layout (q=l16, key=quad*8+j).
// ---------------------------------------------------------------------------
__global__ __launch_bounds__(256)
void attn_kernel(const u16* __restrict__ Q, const u16* __restrict__ Kb,
                 const u16* __restrict__ Vt, u16* __restrict__ O) {
    constexpr int KST = 72;  // K/V LDS row stride (elements)
    constexpr int PST = 72;  // P LDS row stride (elements)
    __shared__ alignas(16) u16 Ks[64 * KST];
    __shared__ alignas(16) u16 Vs[64 * KST];
    __shared__ alignas(16) u16 Ps[4 * 16 * PST];

    const int qt = blockIdx.x, bh = blockIdx.y;
    const int tid = threadIdx.x;
    const int wave = tid >> 6, lane = tid & 63;
    const int quad = lane >> 4, l16 = lane & 15;

    const u16* Qh = Q  + (size_t)bh * TT * DH;
    const u16* Kh = Kb + (size_t)bh * TT * DH;
    const u16* Vh = Vt + (size_t)bh * DH * TT;

    const int qrow = qt * 64 + wave * 16;

    // Q fragments (A-operand): row = l16, d = s*32 + quad*8 .. +8
    bf16x8 fq[2];
    fq[0] = *(const bf16x8*)&Qh[(qrow + l16) * DH + quad * 8];
    fq[1] = *(const bf16x8*)&Qh[(qrow + l16) * DH + 32 + quad * 8];

    f32x4 Oacc[4] = {};
    float m_i[4], l_i[4];
    #pragma unroll
    for (int r = 0; r < 4; ++r) { m_i[r] = -INFINITY; l_i[r] = 0.f; }

    u16* Pw = &Ps[wave * 16 * PST];

    for (int j = 0; j <= qt; ++j) {
        __syncthreads();
        // Stage K tile [key][d] and V^T tile [d][key] (both stride KST)
        {
            const int i0 = tid, i1 = tid + 256;
            *(uint4*)&Ks[(i0 >> 3) * KST + (i0 & 7) * 8] =
                *(const uint4*)&Kh[(j * 64 + (i0 >> 3)) * DH + (i0 & 7) * 8];
            *(uint4*)&Ks[(i1 >> 3) * KST + (i1 & 7) * 8] =
                *(const uint4*)&Kh[(j * 64 + (i1 >> 3)) * DH + (i1 & 7) * 8];
            *(uint4*)&Vs[(i0 >> 3) * KST + (i0 & 7) * 8] =
                *(const uint4*)&Vh[(i0 >> 3) * TT + j * 64 + (i0 & 7) * 8];
            *(uint4*)&Vs[(i1 >> 3) * KST + (i1 & 7) * 8] =
                *(const uint4*)&Vh[(i1 >> 3) * TT + j * 64 + (i1 & 7) * 8];
        }
        __syncthreads();

        // S = Q K^T  (16 q-rows x 64 keys), 2 k-steps of 32 over d
        f32x4 s[4];
        #pragma unroll
        for (int nt = 0; nt < 4; ++nt) {
            bf16x8 fk0 = *(const bf16x8*)&Ks[(nt * 16 + l16) * KST + quad * 8];
            bf16x8 fk1 = *(const bf16x8*)&Ks[(nt * 16 + l16) * KST + 32 + quad * 8];
            f32x4 t = {};
            t = __builtin_amdgcn_mfma_f32_16x16x32_bf16(fq[0], fk0, t, 0, 0, 0);
            t = __builtin_amdgcn_mfma_f32_16x16x32_bf16(fq[1], fk1, t, 0, 0, 0);
            s[nt] = t;
        }

        // scale + causal mask + row max
        float rowmax[4] = {-INFINITY, -INFINITY, -INFINITY, -INFINITY};
        #pragma unroll
        for (int nt = 0; nt < 4; ++nt) {
            const int kg = j * 64 + nt * 16 + l16;
            #pragma unroll
            for (int reg = 0; reg < 4; ++reg) {
                const int qg = qt * 64 + wave * 16 + quad * 4 + reg;
                float v = s[nt][reg] * 0.125f;
                v = (kg <= qg) ? v : -INFINITY;
                s[nt][reg] = v;
                rowmax[reg] = fmaxf(rowmax[reg], v);
            }
        }
        #pragma unroll
        for (int off = 1; off < 16; off <<= 1)
            #pragma unroll
            for (int reg = 0; reg < 4; ++reg)
                rowmax[reg] = fmaxf(rowmax[reg], __shfl_xor(rowmax[reg], off, 64));

        float alpha[4];
        #pragma unroll
        for (int reg = 0; reg < 4; ++reg) {
            const float mnew = fmaxf(m_i[reg], rowmax[reg]);
            alpha[reg] = __expf(m_i[reg] - mnew);
            m_i[reg] = mnew;
        }

        float rowsum[4] = {0.f, 0.f, 0.f, 0.f};
        #pragma unroll
        for (int nt = 0; nt < 4; ++nt)
            #pragma unroll
            for (int reg = 0; reg < 4; ++reg) {
                const float p = __expf(s[nt][reg] - m_i[reg]);
                s[nt][reg] = p;
                rowsum[reg] += p;
            }
        #pragma unroll
        for (int off = 1; off < 16; off <<= 1)
            #pragma unroll
            for (int reg = 0; reg < 4; ++reg)
                rowsum[reg] += __shfl_xor(rowsum[reg], off, 64);

        #pragma unroll
        for (int reg = 0; reg < 4; ++reg)
            l_i[reg] = l_i[reg] * alpha[reg] + rowsum[reg];
        #pragma unroll
        for (int dt = 0; dt < 4; ++dt)
            #pragma unroll
            for (int reg = 0; reg < 4; ++reg)
                Oacc[dt][reg] *= alpha[reg];

        // P: C-layout -> LDS [q][key] row-major (per-wave region)
        #pragma unroll
        for (int nt = 0; nt < 4; ++nt)
            #pragma unroll
            for (int reg = 0; reg < 4; ++reg)
                Pw[(quad * 4 + reg) * PST + nt * 16 + l16] = f2bf(s[nt][reg]);

        // Barrier: orders the u16 P-writes before the bf16x8 P-reads.
        __syncthreads();

        // O += P V   (A = P[q][key], B = V[key][d] read from V^T LDS tile)
        #pragma unroll
        for (int st = 0; st < 2; ++st) {
            bf16x8 fp = *(const bf16x8*)&Pw[l16 * PST + st * 32 + quad * 8];
            #pragma unroll
            for (int dt = 0; dt < 4; ++dt) {
                bf16x8 fv = *(const bf16x8*)&Vs[(dt * 16 + l16) * KST + st * 32 + quad * 8];
                Oacc[dt] = __builtin_amdgcn_mfma_f32_16x16x32_bf16(fp, fv, Oacc[dt], 0, 0, 0);
            }
        }
    }

    // Epilogue: O row = q (quad*4+reg), col = d (dt*16+l16); write (B,T,C)
    const int b = bh >> 4, h = bh & 15;
    #pragma unroll
    for (int dt = 0; dt < 4; ++dt)
        #pragma unroll
        for (int reg = 0; reg < 4; ++reg) {
            const float v = Oacc[dt][reg] / l_i[reg];
            const int t = qrow + quad * 4 + reg;
            O[((size_t)(b * TT + t)) * CD + h * DH + dt * 16 + l16] = f2bf(v);
        }
}

// ---------------------------------------------------------------------------
extern "C" void kernel_launch(void* const* d_in, const int* in_sizes, int n_in,
                              void* d_out, int out_size, void* d_ws, size_t ws_size,
                              hipStream_t stream) {
    (void)in_sizes; (void)n_in; (void)out_size; (void)ws_size;
    const float* x    = (const float*)d_in[0];   // (4096, 1024) fp32
    const float* Wqkv = (const float*)d_in[1];   // (1024, 3072) fp32
    const float* Wo   = (const float*)d_in[2];   // (1024, 1024) fp32
    float* out = (float*)d_out;                  // (4096, 1024) fp32

    char* ws = (char*)d_ws;
    u16* xb    = (u16*)(ws + 0);                    // 4096x1024  (8 MB)
    u16* WqkvT = (u16*)(ws + (8u  << 20));          // 3072x1024  (6 MB)
    u16* WoT   = (u16*)(ws + (14u << 20));          // 1024x1024  (2 MB)
    u16* Qb    = (u16*)(ws + (16u << 20));          // (B,H,T,64) (8 MB)
    u16* Kb    = (u16*)(ws + (24u << 20));          // (B,H,T,64) (8 MB)
    u16* Vt    = (u16*)(ws + (32u << 20));          // (B,H,64,T) (8 MB)
    u16* attn  = (u16*)(ws + (40u << 20));          // (B,T,C)    (8 MB)

    convert_f32_bf16<<<BT * CD / (256 * 8), 256, 0, stream>>>(x, xb, BT * CD);
    transpose_f32_bf16<<<dim3(3072 / 32, 1024 / 32), dim3(32, 8), 0, stream>>>(
        Wqkv, WqkvT, 1024, 3072);
    transpose_f32_bf16<<<dim3(1024 / 32, 1024 / 32), dim3(32, 8), 0, stream>>>(
        Wo, WoT, 1024, 1024);

    // qkv = x @ W_qkv, scattered to Q/K (B,H,T,64) and V^T (B,H,64,T)
    gemm_bt<1><<<dim3(3072 / 128, BT / 128), 256, 0, stream>>>(
        xb, WqkvT, Qb, Kb, Vt, nullptr, BT, 3072, CD);

    attn_kernel<<<dim3(TT / 64, BB * HH), 256, 0, stream>>>(Qb, Kb, Vt, attn);

    // out = attn @ W_o  (fp32 store to d_out)
    gemm_bt<0><<<dim3(CD / 128, BT / 128), 256, 0, stream>>>(
        attn, WoT, nullptr, nullptr, nullptr, out, BT, CD, CD);
}

// Round 7
// 226.971 us; speedup vs baseline: 1.2431x; 1.2431x over previous
//
#include <hip/hip_runtime.h>

typedef unsigned short u16;
typedef unsigned int u32;
typedef __bf16 bf16x8 __attribute__((ext_vector_type(8)));
typedef float f32x4 __attribute__((ext_vector_type(4)));

#define DEV __device__ __forceinline__

// Problem constants (B,T,D_MODEL,H) = (2,2048,1024,16)
constexpr int BB = 2;
constexpr int TT = 2048;
constexpr int CD = 1024;
constexpr int HH = 16;
constexpr int DH = 64;
constexpr int BT = BB * TT;   // 4096

DEV u16 f2bf(float f) {
    u32 u = __builtin_bit_cast(u32, f);
    u32 r = u + 0x7FFFu + ((u >> 16) & 1u);
    return (u16)(r >> 16);
}

DEV f32x4 mfma16(bf16x8 a, bf16x8 b, f32x4 c) {
    return __builtin_amdgcn_mfma_f32_16x16x32_bf16(a, b, c, 0, 0, 0);
}

// Async global->LDS, 16B per lane: LDS dest = wave-uniform base + lane*16.
DEV void gld_lds16(u16* lds, const u16* g) {
    __builtin_amdgcn_global_load_lds(
        (const __attribute__((address_space(1))) unsigned int*)g,
        (__attribute__((address_space(3))) unsigned int*)lds, 16, 0, 0);
}

// ---------------------------------------------------------------------------
// Elementwise fp32 -> bf16 convert. n must be a multiple of 2048.
// ---------------------------------------------------------------------------
__global__ __launch_bounds__(256)
void convert_f32_bf16(const float* __restrict__ in, u16* __restrict__ out, int n) {
    const int i = (blockIdx.x * 256 + threadIdx.x) * 8;
    if (i >= n) return;
    float4 a = *(const float4*)&in[i];
    float4 b = *(const float4*)&in[i + 4];
    u16 t[8];
    t[0] = f2bf(a.x); t[1] = f2bf(a.y); t[2] = f2bf(a.z); t[3] = f2bf(a.w);
    t[4] = f2bf(b.x); t[5] = f2bf(b.y); t[6] = f2bf(b.z); t[7] = f2bf(b.w);
    *(uint4*)&out[i] = *(const uint4*)t;
}

// ---------------------------------------------------------------------------
// Fused transpose + fp32->bf16: out[c][r] = bf16(in[r][c]).
// ---------------------------------------------------------------------------
__global__ __launch_bounds__(256)
void transpose_f32_bf16(const float* __restrict__ in, u16* __restrict__ out,
                        int rows, int cols) {
    __shared__ u16 tile[32][33];
    const int c0 = blockIdx.x * 32, r0 = blockIdx.y * 32;
    const int tx = threadIdx.x, ty = threadIdx.y;
    #pragma unroll
    for (int i = ty; i < 32; i += 8)
        tile[i][tx] = f2bf(in[(r0 + i) * cols + (c0 + tx)]);
    __syncthreads();
    #pragma unroll
    for (int i = ty; i < 32; i += 8)
        out[(c0 + i) * rows + (r0 + tx)] = tile[tx][i];
}

// ---------------------------------------------------------------------------
// GEMM: C[M][N] = A[M][K] * Bt[N][K]^T,  bf16 in, fp32 acc.
// 128x128 tile, BK=32, global_load_lds width-16 staging (m97 pattern);
// exonerated by round5==round6 output equivalence.  LDS stride 32 elems
// (64 B, unpadded — required by lane-contiguous DMA).
// EPI==0: fp32 store to outf.  EPI==1: QKV scatter (bf16 Q,K,V^T).
// ---------------------------------------------------------------------------
template <int EPI>
__global__ __launch_bounds__(256)
void gemm_bt(const u16* __restrict__ A, const u16* __restrict__ Bt,
             u16* __restrict__ out0, u16* __restrict__ out1,
             u16* __restrict__ out2, float* __restrict__ outf,
             int M, int N, int K) {
    constexpr int BM = 128, BN = 128, BK = 32, AST = 32;
    __shared__ alignas(16) u16 As[BM * AST];
    __shared__ alignas(16) u16 Bs[BN * AST];

    const int tid  = threadIdx.x;
    const int wave = tid >> 6, lane = tid & 63;
    const int quad = lane >> 4, l16 = lane & 15;
    const int wm = (wave & 1) * 64, wn = (wave >> 1) * 64;
    const int m0 = blockIdx.y * BM, n0 = blockIdx.x * BN;

    // Staging: wave w covers tile rows w*32..w*32+31; per instruction the 64
    // lanes cover 16 rows x 64 B: lane -> (row = lane/4, col = lane%4*8).
    const int srow = wave * 32 + (lane >> 2);
    const int scol = (lane & 3) * 8;
    const u16* ga0 = A  + (size_t)(m0 + srow) * K + scol;
    const u16* ga1 = ga0 + (size_t)16 * K;
    const u16* gb0 = Bt + (size_t)(n0 + srow) * K + scol;
    const u16* gb1 = gb0 + (size_t)16 * K;
    u16* la0 = As + wave * 1024;
    u16* la1 = As + wave * 1024 + 512;
    u16* lb0 = Bs + wave * 1024;
    u16* lb1 = Bs + wave * 1024 + 512;

    f32x4 acc[4][4] = {};

    for (int k0 = 0; k0 < K; k0 += BK) {
        gld_lds16(la0, ga0 + k0);
        gld_lds16(la1, ga1 + k0);
        gld_lds16(lb0, gb0 + k0);
        gld_lds16(lb1, gb1 + k0);
        __syncthreads();   // vmcnt drain -> LDS staged

        bf16x8 fa[4], fb[4];
        #pragma unroll
        for (int mt = 0; mt < 4; ++mt)
            fa[mt] = *(const bf16x8*)&As[(wm + mt * 16 + l16) * AST + quad * 8];
        #pragma unroll
        for (int nt = 0; nt < 4; ++nt)
            fb[nt] = *(const bf16x8*)&Bs[(wn + nt * 16 + l16) * AST + quad * 8];
        #pragma unroll
        for (int mt = 0; mt < 4; ++mt)
            #pragma unroll
            for (int nt = 0; nt < 4; ++nt)
                acc[mt][nt] = mfma16(fa[mt], fb[nt], acc[mt][nt]);
        __syncthreads();
    }

    // Epilogue. C/D layout: row = quad*4+reg, col = l16.
    #pragma unroll
    for (int mt = 0; mt < 4; ++mt) {
        #pragma unroll
        for (int nt = 0; nt < 4; ++nt) {
            #pragma unroll
            for (int reg = 0; reg < 4; ++reg) {
                const int r = m0 + wm + mt * 16 + quad * 4 + reg;
                const int c = n0 + wn + nt * 16 + l16;
                if (EPI == 0) {
                    outf[(size_t)r * N + c] = acc[mt][nt][reg];
                } else {
                    const u16 v = f2bf(acc[mt][nt][reg]);
                    const int which = c >> 10;       // 0=q 1=k 2=v
                    const int cc = c & 1023;
                    const int h = cc >> 6, d = cc & 63;
                    const int b = r >> 11, t = r & 2047;
                    const int bh = b * HH + h;
                    if (which == 0)      out0[((size_t)bh * TT + t) * DH + d] = v;
                    else if (which == 1) out1[((size_t)bh * TT + t) * DH + d] = v;
                    else                 out2[((size_t)bh * DH + d) * TT + t] = v;
                }
            }
        }
    }
}

// ---------------------------------------------------------------------------
// Flash attention v2 (causal), load-balanced + software-pipelined.
// Grid (16, B*H); block p handles q-tiles qtA=31-p and qtB=p  ->  exactly 33
// tile-chunk computations per block.  K/V double-buffered in LDS; next chunk
// loaded to registers during compute (1 barrier per chunk).
// BUGFIX (r6): diagonal mask q-row is wave*16 + quad*4 + reg (the wave*16
// term was dropped in v2 — waves 1..3 over-masked their diagonal tiles;
// deterministic absmax 3.52 in rounds 5 & 6).
// ---------------------------------------------------------------------------
constexpr int KST = 72;  // K/V LDS row stride (144 B)
constexpr int PST = 72;

DEV void attn_step(const u16* __restrict__ Ksb, const u16* __restrict__ Vsb,
                   u16* __restrict__ Pw, const bf16x8* fq, f32x4* Oacc,
                   float* m_i, float* l_i, bool diag,
                   int wave, int quad, int l16) {
    // S = Q K^T  (16 q-rows x 64 keys)
    f32x4 s[4];
    #pragma unroll
    for (int nt = 0; nt < 4; ++nt) {
        bf16x8 fk0 = *(const bf16x8*)&Ksb[(nt * 16 + l16) * KST + quad * 8];
        bf16x8 fk1 = *(const bf16x8*)&Ksb[(nt * 16 + l16) * KST + 32 + quad * 8];
        f32x4 t = {};
        t = mfma16(fq[0], fk0, t);
        t = mfma16(fq[1], fk1, t);
        s[nt] = t;
    }

    float rowmax[4] = {-INFINITY, -INFINITY, -INFINITY, -INFINITY};
    #pragma unroll
    for (int nt = 0; nt < 4; ++nt) {
        #pragma unroll
        for (int reg = 0; reg < 4; ++reg) {
            float v = s[nt][reg] * 0.125f;
            if (diag) {
                const int kg = nt * 16 + l16;               // key, tile-local
                const int qg = wave * 16 + quad * 4 + reg;  // q row, tile-local
                v = (kg <= qg) ? v : -INFINITY;
            }
            s[nt][reg] = v;
            rowmax[reg] = fmaxf(rowmax[reg], v);
        }
    }
    #pragma unroll
    for (int off = 1; off < 16; off <<= 1)
        #pragma unroll
        for (int reg = 0; reg < 4; ++reg)
            rowmax[reg] = fmaxf(rowmax[reg], __shfl_xor(rowmax[reg], off, 64));

    float alpha[4];
    #pragma unroll
    for (int reg = 0; reg < 4; ++reg) {
        const float mnew = fmaxf(m_i[reg], rowmax[reg]);
        alpha[reg] = __expf(m_i[reg] - mnew);
        m_i[reg] = mnew;
    }

    float rowsum[4] = {0.f, 0.f, 0.f, 0.f};
    #pragma unroll
    for (int nt = 0; nt < 4; ++nt)
        #pragma unroll
        for (int reg = 0; reg < 4; ++reg) {
            const float pv = __expf(s[nt][reg] - m_i[reg]);
            s[nt][reg] = pv;
            rowsum[reg] += pv;
        }
    #pragma unroll
    for (int off = 1; off < 16; off <<= 1)
        #pragma unroll
        for (int reg = 0; reg < 4; ++reg)
            rowsum[reg] += __shfl_xor(rowsum[reg], off, 64);

    #pragma unroll
    for (int reg = 0; reg < 4; ++reg)
        l_i[reg] = l_i[reg] * alpha[reg] + rowsum[reg];
    #pragma unroll
    for (int dt = 0; dt < 4; ++dt)
        #pragma unroll
        for (int reg = 0; reg < 4; ++reg)
            Oacc[dt][reg] *= alpha[reg];

    // P: C-layout -> per-wave LDS [q][key]; compiler-reorder guards only
    // (per-wave region; DS pipe in-order within a wave; exonerated by
    // round5==round6 equivalence).
    asm volatile("" ::: "memory");
    #pragma unroll
    for (int nt = 0; nt < 4; ++nt)
        #pragma unroll
        for (int reg = 0; reg < 4; ++reg)
            Pw[(quad * 4 + reg) * PST + nt * 16 + l16] = f2bf(s[nt][reg]);
    asm volatile("" ::: "memory");

    // O += P V
    #pragma unroll
    for (int st = 0; st < 2; ++st) {
        bf16x8 fp = *(const bf16x8*)&Pw[l16 * PST + st * 32 + quad * 8];
        #pragma unroll
        for (int dt = 0; dt < 4; ++dt) {
            bf16x8 fv = *(const bf16x8*)&Vsb[(dt * 16 + l16) * KST + st * 32 + quad * 8];
            Oacc[dt] = mfma16(fp, fv, Oacc[dt]);
        }
    }
}

__global__ __launch_bounds__(256)
void attn_kernel(const u16* __restrict__ Q, const u16* __restrict__ Kb,
                 const u16* __restrict__ Vt, u16* __restrict__ O) {
    __shared__ alignas(16) u16 Ks[2][64 * KST];
    __shared__ alignas(16) u16 Vs[2][64 * KST];
    __shared__ alignas(16) u16 Ps[4 * 16 * PST];

    const int p = blockIdx.x;         // 0..15
    const int bh = blockIdx.y;
    const int qtA = 31 - p;           // big tile; also jmax
    const int qtB = p;                // small tile
    const int jmax = qtA;

    const int tid = threadIdx.x;
    const int wave = tid >> 6, lane = tid & 63;
    const int quad = lane >> 4, l16 = lane & 15;

    const u16* Qh = Q  + (size_t)bh * TT * DH;
    const u16* Kh = Kb + (size_t)bh * TT * DH;
    const u16* Vh = Vt + (size_t)bh * DH * TT;

    const int rowA = qtA * 64 + wave * 16;
    const int rowB = qtB * 64 + wave * 16;

    bf16x8 fqA[2], fqB[2];
    fqA[0] = *(const bf16x8*)&Qh[(rowA + l16) * DH + quad * 8];
    fqA[1] = *(const bf16x8*)&Qh[(rowA + l16) * DH + 32 + quad * 8];
    fqB[0] = *(const bf16x8*)&Qh[(rowB + l16) * DH + quad * 8];
    fqB[1] = *(const bf16x8*)&Qh[(rowB + l16) * DH + 32 + quad * 8];

    f32x4 OA[4] = {}, OB[4] = {};
    float mA[4], lA[4], mB[4], lB[4];
    #pragma unroll
    for (int r = 0; r < 4; ++r) {
        mA[r] = -INFINITY; lA[r] = 0.f;
        mB[r] = -INFINITY; lB[r] = 0.f;
    }
    u16* Pw = &Ps[wave * 16 * PST];

    // Chunk staging: thread i covers 16B at K row (i>>3) col (i&7)*8, +row32.
    const int trow = tid >> 3, tcol = (tid & 7) * 8;
    uint4 kr0, kr1, vr0, vr1;

    auto load_chunk = [&](int j) {
        const u16* ks = Kh + (size_t)j * 64 * DH;
        kr0 = *(const uint4*)&ks[trow * DH + tcol];
        kr1 = *(const uint4*)&ks[(trow + 32) * DH + tcol];
        const u16* vs = Vh + (size_t)j * 64;
        vr0 = *(const uint4*)&vs[(size_t)trow * TT + tcol];
        vr1 = *(const uint4*)&vs[(size_t)(trow + 32) * TT + tcol];
    };
    auto write_chunk = [&](int buf) {
        *(uint4*)&Ks[buf][trow * KST + tcol]        = kr0;
        *(uint4*)&Ks[buf][(trow + 32) * KST + tcol] = kr1;
        *(uint4*)&Vs[buf][trow * KST + tcol]        = vr0;
        *(uint4*)&Vs[buf][(trow + 32) * KST + tcol] = vr1;
    };

    load_chunk(0);
    write_chunk(0);

    for (int j = 0; j <= jmax; ++j) {
        const int cur = j & 1;
        __syncthreads();                    // buf[cur] staged & visible
        if (j < jmax) load_chunk(j + 1);    // loads fly during compute
        attn_step(Ks[cur], Vs[cur], Pw, fqA, OA, mA, lA, (j == qtA),
                  wave, quad, l16);
        if (j <= qtB)
            attn_step(Ks[cur], Vs[cur], Pw, fqB, OB, mB, lB, (j == qtB),
                      wave, quad, l16);
        if (j < jmax) write_chunk(cur ^ 1); // after all buf[cur^1] readers done
    }

    // Epilogue: row = quad*4+reg, col(d) = dt*16+l16; write (B,T,C) bf16
    const int b = bh >> 4, h = bh & 15;
    #pragma unroll
    for (int dt = 0; dt < 4; ++dt)
        #pragma unroll
        for (int reg = 0; reg < 4; ++reg) {
            const int tA = rowA + quad * 4 + reg;
            const int tB = rowB + quad * 4 + reg;
            O[((size_t)(b * TT + tA)) * CD + h * DH + dt * 16 + l16] =
                f2bf(OA[dt][reg] / lA[reg]);
            O[((size_t)(b * TT + tB)) * CD + h * DH + dt * 16 + l16] =
                f2bf(OB[dt][reg] / lB[reg]);
        }
}

// ---------------------------------------------------------------------------
extern "C" void kernel_launch(void* const* d_in, const int* in_sizes, int n_in,
                              void* d_out, int out_size, void* d_ws, size_t ws_size,
                              hipStream_t stream) {
    (void)in_sizes; (void)n_in; (void)out_size; (void)ws_size;
    const float* x    = (const float*)d_in[0];   // (4096, 1024) fp32
    const float* Wqkv = (const float*)d_in[1];   // (1024, 3072) fp32
    const float* Wo   = (const float*)d_in[2];   // (1024, 1024) fp32
    float* out = (float*)d_out;                  // (4096, 1024) fp32

    char* ws = (char*)d_ws;
    u16* xb    = (u16*)(ws + 0);                    // 4096x1024  (8 MB)
    u16* WqkvT = (u16*)(ws + (8u  << 20));          // 3072x1024  (6 MB)
    u16* WoT   = (u16*)(ws + (14u << 20));          // 1024x1024  (2 MB)
    u16* Qb    = (u16*)(ws + (16u << 20));          // (B,H,T,64) (8 MB)
    u16* Kb    = (u16*)(ws + (24u << 20));          // (B,H,T,64) (8 MB)
    u16* Vt    = (u16*)(ws + (32u << 20));          // (B,H,64,T) (8 MB)
    u16* attn  = (u16*)(ws + (40u << 20));          // (B,T,C)    (8 MB)

    convert_f32_bf16<<<BT * CD / (256 * 8), 256, 0, stream>>>(x, xb, BT * CD);
    transpose_f32_bf16<<<dim3(3072 / 32, 1024 / 32), dim3(32, 8), 0, stream>>>(
        Wqkv, WqkvT, 1024, 3072);
    transpose_f32_bf16<<<dim3(1024 / 32, 1024 / 32), dim3(32, 8), 0, stream>>>(
        Wo, WoT, 1024, 1024);

    // qkv = x @ W_qkv, scattered to Q/K (B,H,T,64) and V^T (B,H,64,T)
    gemm_bt<1><<<dim3(3072 / 128, BT / 128), 256, 0, stream>>>(
        xb, WqkvT, Qb, Kb, Vt, nullptr, BT, 3072, CD);

    attn_kernel<<<dim3(16, BB * HH), 256, 0, stream>>>(Qb, Kb, Vt, attn);

    // out = attn @ W_o  (fp32 store to d_out)
    gemm_bt<0><<<dim3(CD / 128, BT / 128), 256, 0, stream>>>(
        attn, WoT, nullptr, nullptr, nullptr, out, BT, CD, CD);
}

// Round 8
// 216.901 us; speedup vs baseline: 1.3008x; 1.0464x over previous
//
#include <hip/hip_runtime.h>

typedef unsigned short u16;
typedef unsigned int u32;
typedef __bf16 bf16x8 __attribute__((ext_vector_type(8)));
typedef float f32x4 __attribute__((ext_vector_type(4)));

#define DEV __device__ __forceinline__

// Problem constants (B,T,D_MODEL,H) = (2,2048,1024,16)
constexpr int BB = 2;
constexpr int TT = 2048;
constexpr int CD = 1024;
constexpr int HH = 16;
constexpr int DH = 64;
constexpr int BT = BB * TT;   // 4096

DEV u16 f2bf(float f) {
    u32 u = __builtin_bit_cast(u32, f);
    u32 r = u + 0x7FFFu + ((u >> 16) & 1u);
    return (u16)(r >> 16);
}

DEV f32x4 mfma16(bf16x8 a, bf16x8 b, f32x4 c) {
    return __builtin_amdgcn_mfma_f32_16x16x32_bf16(a, b, c, 0, 0, 0);
}

// Async global->LDS, 16B per lane: LDS dest = wave-uniform base + lane*16.
DEV void gld_lds16(u16* lds, const u16* g) {
    __builtin_amdgcn_global_load_lds(
        (const __attribute__((address_space(1))) unsigned int*)g,
        (__attribute__((address_space(3))) unsigned int*)lds, 16, 0, 0);
}

// ---------------------------------------------------------------------------
// Elementwise fp32 -> bf16 convert.
// ---------------------------------------------------------------------------
__global__ __launch_bounds__(256)
void convert_f32_bf16(const float* __restrict__ in, u16* __restrict__ out, int n) {
    const int i = (blockIdx.x * 256 + threadIdx.x) * 8;
    if (i >= n) return;
    float4 a = *(const float4*)&in[i];
    float4 b = *(const float4*)&in[i + 4];
    u16 t[8];
    t[0] = f2bf(a.x); t[1] = f2bf(a.y); t[2] = f2bf(a.z); t[3] = f2bf(a.w);
    t[4] = f2bf(b.x); t[5] = f2bf(b.y); t[6] = f2bf(b.z); t[7] = f2bf(b.w);
    *(uint4*)&out[i] = *(const uint4*)t;
}

// ---------------------------------------------------------------------------
// Fused transpose + fp32->bf16: out[c][r] = bf16(in[r][c]).
// ---------------------------------------------------------------------------
__global__ __launch_bounds__(256)
void transpose_f32_bf16(const float* __restrict__ in, u16* __restrict__ out,
                        int rows, int cols) {
    __shared__ u16 tile[32][33];
    const int c0 = blockIdx.x * 32, r0 = blockIdx.y * 32;
    const int tx = threadIdx.x, ty = threadIdx.y;
    #pragma unroll
    for (int i = ty; i < 32; i += 8)
        tile[i][tx] = f2bf(in[(r0 + i) * cols + (c0 + tx)]);
    __syncthreads();
    #pragma unroll
    for (int i = ty; i < 32; i += 8)
        out[(c0 + i) * rows + (r0 + tx)] = tile[tx][i];
}

// ---------------------------------------------------------------------------
// GEMM: C[M][N] = A[M][K] * Bt[N][K]^T,  bf16 in, fp32 acc.
// 128x128 tile, BK=32, global_load_lds width-16 staging (m97 pattern).
// EPI==0: fp32 store to outf.  EPI==1: QKV scatter (bf16 Q,K,V^T); Q is
// pre-scaled by 1/8 (softmax scale folded in — attention skips it).
// ---------------------------------------------------------------------------
template <int EPI>
__global__ __launch_bounds__(256)
void gemm_bt(const u16* __restrict__ A, const u16* __restrict__ Bt,
             u16* __restrict__ out0, u16* __restrict__ out1,
             u16* __restrict__ out2, float* __restrict__ outf,
             int M, int N, int K) {
    constexpr int BM = 128, BN = 128, BK = 32, AST = 32;
    __shared__ alignas(16) u16 As[BM * AST];
    __shared__ alignas(16) u16 Bs[BN * AST];

    const int tid  = threadIdx.x;
    const int wave = tid >> 6, lane = tid & 63;
    const int quad = lane >> 4, l16 = lane & 15;
    const int wm = (wave & 1) * 64, wn = (wave >> 1) * 64;
    const int m0 = blockIdx.y * BM, n0 = blockIdx.x * BN;

    const int srow = wave * 32 + (lane >> 2);
    const int scol = (lane & 3) * 8;
    const u16* ga0 = A  + (size_t)(m0 + srow) * K + scol;
    const u16* ga1 = ga0 + (size_t)16 * K;
    const u16* gb0 = Bt + (size_t)(n0 + srow) * K + scol;
    const u16* gb1 = gb0 + (size_t)16 * K;
    u16* la0 = As + wave * 1024;
    u16* la1 = As + wave * 1024 + 512;
    u16* lb0 = Bs + wave * 1024;
    u16* lb1 = Bs + wave * 1024 + 512;

    f32x4 acc[4][4] = {};

    for (int k0 = 0; k0 < K; k0 += BK) {
        gld_lds16(la0, ga0 + k0);
        gld_lds16(la1, ga1 + k0);
        gld_lds16(lb0, gb0 + k0);
        gld_lds16(lb1, gb1 + k0);
        __syncthreads();

        bf16x8 fa[4], fb[4];
        #pragma unroll
        for (int mt = 0; mt < 4; ++mt)
            fa[mt] = *(const bf16x8*)&As[(wm + mt * 16 + l16) * AST + quad * 8];
        #pragma unroll
        for (int nt = 0; nt < 4; ++nt)
            fb[nt] = *(const bf16x8*)&Bs[(wn + nt * 16 + l16) * AST + quad * 8];
        #pragma unroll
        for (int mt = 0; mt < 4; ++mt)
            #pragma unroll
            for (int nt = 0; nt < 4; ++nt)
                acc[mt][nt] = mfma16(fa[mt], fb[nt], acc[mt][nt]);
        __syncthreads();
    }

    // Epilogue. C/D layout: row = quad*4+reg, col = l16.
    #pragma unroll
    for (int mt = 0; mt < 4; ++mt) {
        #pragma unroll
        for (int nt = 0; nt < 4; ++nt) {
            #pragma unroll
            for (int reg = 0; reg < 4; ++reg) {
                const int r = m0 + wm + mt * 16 + quad * 4 + reg;
                const int c = n0 + wn + nt * 16 + l16;
                if (EPI == 0) {
                    outf[(size_t)r * N + c] = acc[mt][nt][reg];
                } else {
                    const int which = c >> 10;       // 0=q 1=k 2=v
                    const int cc = c & 1023;
                    const int h = cc >> 6, d = cc & 63;
                    const int b = r >> 11, t = r & 2047;
                    const int bh = b * HH + h;
                    if (which == 0) {
                        // fold softmax scale 1/sqrt(64) into Q
                        out0[((size_t)bh * TT + t) * DH + d] =
                            f2bf(acc[mt][nt][reg] * 0.125f);
                    } else if (which == 1) {
                        out1[((size_t)bh * TT + t) * DH + d] = f2bf(acc[mt][nt][reg]);
                    } else {
                        out2[((size_t)bh * DH + d) * TT + t] = f2bf(acc[mt][nt][reg]);
                    }
                }
            }
        }
    }
}

// ---------------------------------------------------------------------------
// Flash attention v3 (causal): S^T formulation.
//   S^T = K·Q^T via mfma(A=K_frag, B=Q_frag)  ->  C[key=quad*4+reg][q=l16].
//   Per-lane softmax state is SCALAR (one q-row per lane); row reductions are
//   15 in-register ops + 2 cross-quad shuffles.
//   PV: O^T[d][q] = V^T·P^T with zero-padded K=32 MFMA: logical k=quad*8+j
//   maps to key=quad*4+j for j<4 (zeros j>=4) on BOTH operands — P^T comes
//   straight from C-layout registers, NO LDS round-trip.
// Grid (16, B*H); block p handles q-tiles 31-p and p (33 chunks, balanced).
// K/V double-buffered in LDS, next chunk prefetched to registers.
// ---------------------------------------------------------------------------
constexpr int KST = 72;  // K/V LDS row stride (144 B, 16B-aligned rows)

DEV void attn_step(const u16* __restrict__ Ksb, const u16* __restrict__ Vsb,
                   const bf16x8* fq, f32x4* Oacc,
                   float& m_i, float& l_i, bool diag,
                   int wave, int quad, int l16) {
    // S^T: 4 key-tiles x (2 k-steps over d)
    f32x4 st[4];
    #pragma unroll
    for (int nt = 0; nt < 4; ++nt) {
        bf16x8 fk0 = *(const bf16x8*)&Ksb[(nt * 16 + l16) * KST + quad * 8];
        bf16x8 fk1 = *(const bf16x8*)&Ksb[(nt * 16 + l16) * KST + 32 + quad * 8];
        f32x4 t = {};
        t = mfma16(fk0, fq[0], t);   // A=K (m=key), B=Q (n=q)
        t = mfma16(fk1, fq[1], t);
        st[nt] = t;
    }

    // causal mask on diagonal tile: key_loc <= q_loc (scale pre-folded in Q)
    if (diag) {
        const int qg = wave * 16 + l16;
        #pragma unroll
        for (int nt = 0; nt < 4; ++nt)
            #pragma unroll
            for (int reg = 0; reg < 4; ++reg) {
                const int kg = nt * 16 + quad * 4 + reg;
                st[nt][reg] = (kg <= qg) ? st[nt][reg] : -INFINITY;
            }
    }

    // row max: 15 in-register + 2 cross-quad shuffles
    float vmax = st[0][0];
    #pragma unroll
    for (int nt = 0; nt < 4; ++nt)
        #pragma unroll
        for (int reg = 0; reg < 4; ++reg)
            vmax = fmaxf(vmax, st[nt][reg]);
    vmax = fmaxf(vmax, __shfl_xor(vmax, 16, 64));
    vmax = fmaxf(vmax, __shfl_xor(vmax, 32, 64));

    const float mnew = fmaxf(m_i, vmax);
    const float alpha = __expf(m_i - mnew);
    m_i = mnew;

    float vsum = 0.f;
    #pragma unroll
    for (int nt = 0; nt < 4; ++nt)
        #pragma unroll
        for (int reg = 0; reg < 4; ++reg) {
            const float p = __expf(st[nt][reg] - mnew);
            st[nt][reg] = p;
            vsum += p;
        }
    vsum += __shfl_xor(vsum, 16, 64);
    vsum += __shfl_xor(vsum, 32, 64);
    l_i = l_i * alpha + vsum;

    #pragma unroll
    for (int dt = 0; dt < 4; ++dt)
        #pragma unroll
        for (int reg = 0; reg < 4; ++reg)
            Oacc[dt][reg] *= alpha;

    // P^T -> zero-padded B-operand (reg j = key quad*4+j, j<4)
    bf16x8 pb[4];
    #pragma unroll
    for (int nt = 0; nt < 4; ++nt) {
        u16 pa[8];
        #pragma unroll
        for (int reg = 0; reg < 4; ++reg) pa[reg] = f2bf(st[nt][reg]);
        pa[4] = pa[5] = pa[6] = pa[7] = 0;
        pb[nt] = *(const bf16x8*)pa;
    }

    // O^T += V^T · P^T   (A = V^T: m=d=l16, k-> key quad*4+j zero-padded)
    #pragma unroll
    for (int nt = 0; nt < 4; ++nt) {
        #pragma unroll
        for (int dt = 0; dt < 4; ++dt) {
            u16 va[8];
            *(uint2*)va = *(const uint2*)&Vsb[(dt * 16 + l16) * KST + nt * 16 + quad * 4];
            va[4] = va[5] = va[6] = va[7] = 0;
            bf16x8 fv = *(const bf16x8*)va;
            Oacc[dt] = mfma16(fv, pb[nt], Oacc[dt]);
        }
    }
}

__global__ __launch_bounds__(256)
void attn_kernel(const u16* __restrict__ Q, const u16* __restrict__ Kb,
                 const u16* __restrict__ Vt, u16* __restrict__ O) {
    __shared__ alignas(16) u16 Ks[2][64 * KST];
    __shared__ alignas(16) u16 Vs[2][64 * KST];

    const int p = blockIdx.x;         // 0..15
    const int bh = blockIdx.y;
    const int qtA = 31 - p;           // big tile; also jmax
    const int qtB = p;                // small tile
    const int jmax = qtA;

    const int tid = threadIdx.x;
    const int wave = tid >> 6, lane = tid & 63;
    const int quad = lane >> 4, l16 = lane & 15;

    const u16* Qh = Q  + (size_t)bh * TT * DH;
    const u16* Kh = Kb + (size_t)bh * TT * DH;
    const u16* Vh = Vt + (size_t)bh * DH * TT;

    const int rowA = qtA * 64 + wave * 16;
    const int rowB = qtB * 64 + wave * 16;

    // Q fragments (B-operand: n = l16 = q, k = quad*8+j over d)
    bf16x8 fqA[2], fqB[2];
    fqA[0] = *(const bf16x8*)&Qh[(rowA + l16) * DH + quad * 8];
    fqA[1] = *(const bf16x8*)&Qh[(rowA + l16) * DH + 32 + quad * 8];
    fqB[0] = *(const bf16x8*)&Qh[(rowB + l16) * DH + quad * 8];
    fqB[1] = *(const bf16x8*)&Qh[(rowB + l16) * DH + 32 + quad * 8];

    f32x4 OA[4] = {}, OB[4] = {};
    float mA = -INFINITY, lA = 0.f, mB = -INFINITY, lB = 0.f;

    // Chunk staging: thread i covers 16B at K row (i>>3) col (i&7)*8, +row32.
    const int trow = tid >> 3, tcol = (tid & 7) * 8;
    uint4 kr0, kr1, vr0, vr1;

    auto load_chunk = [&](int j) {
        const u16* ks = Kh + (size_t)j * 64 * DH;
        kr0 = *(const uint4*)&ks[trow * DH + tcol];
        kr1 = *(const uint4*)&ks[(trow + 32) * DH + tcol];
        const u16* vs = Vh + (size_t)j * 64;
        vr0 = *(const uint4*)&vs[(size_t)trow * TT + tcol];
        vr1 = *(const uint4*)&vs[(size_t)(trow + 32) * TT + tcol];
    };
    auto write_chunk = [&](int buf) {
        *(uint4*)&Ks[buf][trow * KST + tcol]        = kr0;
        *(uint4*)&Ks[buf][(trow + 32) * KST + tcol] = kr1;
        *(uint4*)&Vs[buf][trow * KST + tcol]        = vr0;
        *(uint4*)&Vs[buf][(trow + 32) * KST + tcol] = vr1;
    };

    load_chunk(0);
    write_chunk(0);

    for (int j = 0; j <= jmax; ++j) {
        const int cur = j & 1;
        __syncthreads();                    // buf[cur] staged & visible
        if (j < jmax) load_chunk(j + 1);    // loads fly during compute
        attn_step(Ks[cur], Vs[cur], fqA, OA, mA, lA, (j == qtA),
                  wave, quad, l16);
        if (j <= qtB)
            attn_step(Ks[cur], Vs[cur], fqB, OB, mB, lB, (j == qtB),
                      wave, quad, l16);
        if (j < jmax) write_chunk(cur ^ 1); // after all buf[cur^1] readers done
    }

    // Epilogue: O^T layout row d = quad*4+reg (per dt), col q = l16.
    // Per lane: 4 consecutive d -> one 8 B store per dt. Write (B,T,C) bf16.
    const int b = bh >> 4, h = bh & 15;
    const float rA = 1.f / lA, rB = 1.f / lB;
    #pragma unroll
    for (int dt = 0; dt < 4; ++dt) {
        u16 oa[4], ob[4];
        #pragma unroll
        for (int reg = 0; reg < 4; ++reg) {
            oa[reg] = f2bf(OA[dt][reg] * rA);
            ob[reg] = f2bf(OB[dt][reg] * rB);
        }
        *(uint2*)&O[((size_t)(b * TT + rowA + l16)) * CD + h * DH + dt * 16 + quad * 4] =
            *(const uint2*)oa;
        *(uint2*)&O[((size_t)(b * TT + rowB + l16)) * CD + h * DH + dt * 16 + quad * 4] =
            *(const uint2*)ob;
    }
}

// ---------------------------------------------------------------------------
extern "C" void kernel_launch(void* const* d_in, const int* in_sizes, int n_in,
                              void* d_out, int out_size, void* d_ws, size_t ws_size,
                              hipStream_t stream) {
    (void)in_sizes; (void)n_in; (void)out_size; (void)ws_size;
    const float* x    = (const float*)d_in[0];   // (4096, 1024) fp32
    const float* Wqkv = (const float*)d_in[1];   // (1024, 3072) fp32
    const float* Wo   = (const float*)d_in[2];   // (1024, 1024) fp32
    float* out = (float*)d_out;                  // (4096, 1024) fp32

    char* ws = (char*)d_ws;
    u16* xb    = (u16*)(ws + 0);                    // 4096x1024  (8 MB)
    u16* WqkvT = (u16*)(ws + (8u  << 20));          // 3072x1024  (6 MB)
    u16* WoT   = (u16*)(ws + (14u << 20));          // 1024x1024  (2 MB)
    u16* Qb    = (u16*)(ws + (16u << 20));          // (B,H,T,64) (8 MB)
    u16* Kb    = (u16*)(ws + (24u << 20));          // (B,H,T,64) (8 MB)
    u16* Vt    = (u16*)(ws + (32u << 20));          // (B,H,64,T) (8 MB)
    u16* attn  = (u16*)(ws + (40u << 20));          // (B,T,C)    (8 MB)

    convert_f32_bf16<<<BT * CD / (256 * 8), 256, 0, stream>>>(x, xb, BT * CD);
    transpose_f32_bf16<<<dim3(3072 / 32, 1024 / 32), dim3(32, 8), 0, stream>>>(
        Wqkv, WqkvT, 1024, 3072);
    transpose_f32_bf16<<<dim3(1024 / 32, 1024 / 32), dim3(32, 8), 0, stream>>>(
        Wo, WoT, 1024, 1024);

    // qkv = x @ W_qkv, scattered to Q (pre-scaled) / K (B,H,T,64), V^T (B,H,64,T)
    gemm_bt<1><<<dim3(3072 / 128, BT / 128), 256, 0, stream>>>(
        xb, WqkvT, Qb, Kb, Vt, nullptr, BT, 3072, CD);

    attn_kernel<<<dim3(16, BB * HH), 256, 0, stream>>>(Qb, Kb, Vt, attn);

    // out = attn @ W_o  (fp32 store to d_out)
    gemm_bt<0><<<dim3(CD / 128, BT / 128), 256, 0, stream>>>(
        attn, WoT, nullptr, nullptr, nullptr, out, BT, CD, CD);
}

// Round 9
// 190.708 us; speedup vs baseline: 1.4794x; 1.1373x over previous
//
#include <hip/hip_runtime.h>

typedef unsigned short u16;
typedef unsigned int u32;
typedef __bf16 bf16x8 __attribute__((ext_vector_type(8)));
typedef float f32x4 __attribute__((ext_vector_type(4)));

#define DEV __device__ __forceinline__

// Problem constants (B,T,D_MODEL,H) = (2,2048,1024,16)
constexpr int BB = 2;
constexpr int TT = 2048;
constexpr int CD = 1024;
constexpr int HH = 16;
constexpr int DH = 64;
constexpr int BT = BB * TT;   // 4096

// softmax scale 1/8 folded with log2(e): S' = S/8*log2e, exp(x)=exp2(x')
#define QSCALE 0.18033688011112042f

DEV u16 f2bf(float f) {
    u32 u = __builtin_bit_cast(u32, f);
    u32 r = u + 0x7FFFu + ((u >> 16) & 1u);
    return (u16)(r >> 16);
}

DEV f32x4 mfma16(bf16x8 a, bf16x8 b, f32x4 c) {
    return __builtin_amdgcn_mfma_f32_16x16x32_bf16(a, b, c, 0, 0, 0);
}

// Async global->LDS, 16B per lane: LDS dest = wave-uniform base + lane*16.
DEV void gld_lds16(u16* lds, const u16* g) {
    __builtin_amdgcn_global_load_lds(
        (const __attribute__((address_space(1))) unsigned int*)g,
        (__attribute__((address_space(3))) unsigned int*)lds, 16, 0, 0);
}

// ---------------------------------------------------------------------------
// Fused preprocessing (single launch):
//   blocks [0,2048):      x fp32 -> bf16           (4096x1024)
//   blocks [2048,5120):   W_qkv (1024x3072) -> transposed bf16 (3072x1024)
//   blocks [5120,6144):   W_o   (1024x1024) -> transposed bf16 (1024x1024)
// ---------------------------------------------------------------------------
__global__ __launch_bounds__(256)
void prep_kernel(const float* __restrict__ x, u16* __restrict__ xb,
                 const float* __restrict__ Wqkv, u16* __restrict__ WqkvT,
                 const float* __restrict__ Wo, u16* __restrict__ WoT) {
    const int tid = threadIdx.x;
    int blk = blockIdx.x;
    if (blk < 2048) {                       // convert job
        const int i = (blk * 256 + tid) * 8;
        float4 a = *(const float4*)&x[i];
        float4 b = *(const float4*)&x[i + 4];
        u16 t[8];
        t[0] = f2bf(a.x); t[1] = f2bf(a.y); t[2] = f2bf(a.z); t[3] = f2bf(a.w);
        t[4] = f2bf(b.x); t[5] = f2bf(b.y); t[6] = f2bf(b.z); t[7] = f2bf(b.w);
        *(uint4*)&xb[i] = *(const uint4*)t;
        return;                             // whole block exits (no barrier)
    }
    __shared__ u16 tile[32][33];
    const float* in; u16* out; int rows, cols, bx, by;
    if (blk < 5120) { blk -= 2048; in = Wqkv; out = WqkvT; rows = 1024; cols = 3072; bx = blk % 96; by = blk / 96; }
    else            { blk -= 5120; in = Wo;   out = WoT;   rows = 1024; cols = 1024; bx = blk % 32; by = blk / 32; }
    const int c0 = bx * 32, r0 = by * 32;
    const int tx = tid & 31, ty = tid >> 5;
    #pragma unroll
    for (int i = ty; i < 32; i += 8)
        tile[i][tx] = f2bf(in[(r0 + i) * cols + (c0 + tx)]);
    __syncthreads();
    #pragma unroll
    for (int i = ty; i < 32; i += 8)
        out[(c0 + i) * rows + (r0 + tx)] = tile[tx][i];
}

// ---------------------------------------------------------------------------
// GEMM: C[M][N] = A[M][K] * Bt[N][K]^T,  bf16 in, fp32 acc.
// BM=128, BN template (128 or 64), BK=32, global_load_lds width-16 staging.
// EPI==0: fp32 store to outf.  EPI==1: QKV scatter (bf16 Q,K,V^T); Q is
// pre-scaled by QSCALE (softmax scale + log2e folded in).
// ---------------------------------------------------------------------------
template <int EPI, int BN>
__global__ __launch_bounds__(256)
void gemm_bt(const u16* __restrict__ A, const u16* __restrict__ Bt,
             u16* __restrict__ out0, u16* __restrict__ out1,
             u16* __restrict__ out2, float* __restrict__ outf,
             int M, int N, int K) {
    constexpr int BM = 128, BK = 32, AST = 32;
    constexpr int NT = BN / 32;             // n-tiles per wave
    __shared__ alignas(16) u16 As[BM * AST];
    __shared__ alignas(16) u16 Bs[BN * AST];

    const int tid  = threadIdx.x;
    const int wave = tid >> 6, lane = tid & 63;
    const int quad = lane >> 4, l16 = lane & 15;
    const int wm = (wave & 1) * 64, wn = (wave >> 1) * (BN / 2);
    const int m0 = blockIdx.y * BM, n0 = blockIdx.x * BN;

    // DMA staging: one instr = 64 lanes x 16B = 16 rows x 64B.
    const int srowA = wave * 32 + (lane >> 2);
    const int srowB = wave * (BN / 4) + (lane >> 2);
    const int scol  = (lane & 3) * 8;
    const u16* ga0 = A  + (size_t)(m0 + srowA) * K + scol;
    const u16* ga1 = ga0 + (size_t)16 * K;
    const u16* gb0 = Bt + (size_t)(n0 + srowB) * K + scol;
    const u16* gb1 = gb0 + (size_t)16 * K;
    u16* la0 = As + wave * 1024;
    u16* la1 = As + wave * 1024 + 512;
    u16* lb0 = Bs + wave * (BN * 8);
    u16* lb1 = Bs + wave * (BN * 8) + 512;

    f32x4 acc[4][NT] = {};

    for (int k0 = 0; k0 < K; k0 += BK) {
        gld_lds16(la0, ga0 + k0);
        gld_lds16(la1, ga1 + k0);
        gld_lds16(lb0, gb0 + k0);
        if constexpr (BN == 128) gld_lds16(lb1, gb1 + k0);
        __syncthreads();

        bf16x8 fa[4], fb[NT];
        #pragma unroll
        for (int mt = 0; mt < 4; ++mt)
            fa[mt] = *(const bf16x8*)&As[(wm + mt * 16 + l16) * AST + quad * 8];
        #pragma unroll
        for (int nt = 0; nt < NT; ++nt)
            fb[nt] = *(const bf16x8*)&Bs[(wn + nt * 16 + l16) * AST + quad * 8];
        #pragma unroll
        for (int mt = 0; mt < 4; ++mt)
            #pragma unroll
            for (int nt = 0; nt < NT; ++nt)
                acc[mt][nt] = mfma16(fa[mt], fb[nt], acc[mt][nt]);
        __syncthreads();
    }

    // Epilogue. C/D layout: row = quad*4+reg, col = l16.
    #pragma unroll
    for (int mt = 0; mt < 4; ++mt) {
        #pragma unroll
        for (int nt = 0; nt < NT; ++nt) {
            #pragma unroll
            for (int reg = 0; reg < 4; ++reg) {
                const int r = m0 + wm + mt * 16 + quad * 4 + reg;
                const int c = n0 + wn + nt * 16 + l16;
                if (EPI == 0) {
                    outf[(size_t)r * N + c] = acc[mt][nt][reg];
                } else {
                    const int which = c >> 10;       // 0=q 1=k 2=v
                    const int cc = c & 1023;
                    const int h = cc >> 6, d = cc & 63;
                    const int b = r >> 11, t = r & 2047;
                    const int bh = b * HH + h;
                    if (which == 0) {
                        out0[((size_t)bh * TT + t) * DH + d] =
                            f2bf(acc[mt][nt][reg] * QSCALE);
                    } else if (which == 1) {
                        out1[((size_t)bh * TT + t) * DH + d] = f2bf(acc[mt][nt][reg]);
                    } else {
                        out2[((size_t)bh * DH + d) * TT + t] = f2bf(acc[mt][nt][reg]);
                    }
                }
            }
        }
    }
}

// ---------------------------------------------------------------------------
// Flash attention v4 (causal): S^T formulation + paired-key full-K=32 PV.
//   S^T = K·Q^T  ->  C[key = quad*4+reg (tile nt)][q = l16]; per-lane scalar
//   softmax state in exp2 domain (scale+log2e pre-folded into Q).
//   PV uses the MFMA k-permutation freedom: logical k=quad*8+j maps to
//   physical key pair*32 + (j<4 ? quad*4+j : 16+quad*4+(j-4)) on BOTH
//   operands (cancels). P^T comes directly from the two C-layout S-tiles;
//   V^T LDS columns are stored pair-permuted so fragments are one b128.
// Grid (16, B*H); block p handles q-tiles 31-p and p (33 steps, balanced).
// K/V double-buffered in LDS; next chunk prefetched to registers; K/V
// fragments hoisted once per chunk and shared by both q-tiles.
// ---------------------------------------------------------------------------
constexpr int KST = 72;  // K/V LDS row stride (144 B, rows 16B-aligned)

DEV void attn_step(const bf16x8 fk[4][2], const bf16x8 fv[2][4],
                   const bf16x8* fq, f32x4* Oacc,
                   float& m_i, float& l_i, bool diag,
                   int wave, int quad, int l16) {
    // S^T: 4 key-tiles x 2 k-steps over d
    f32x4 st[4];
    #pragma unroll
    for (int nt = 0; nt < 4; ++nt) {
        f32x4 t = {};
        t = mfma16(fk[nt][0], fq[0], t);   // A=K (m=key), B=Q (n=q)
        t = mfma16(fk[nt][1], fq[1], t);
        st[nt] = t;
    }

    // causal mask on diagonal tile: key_loc <= q_loc
    if (diag) {
        const int qg = wave * 16 + l16;
        #pragma unroll
        for (int nt = 0; nt < 4; ++nt)
            #pragma unroll
            for (int reg = 0; reg < 4; ++reg) {
                const int kg = nt * 16 + quad * 4 + reg;
                st[nt][reg] = (kg <= qg) ? st[nt][reg] : -INFINITY;
            }
    }

    // row max: 15 in-register + 2 cross-quad shuffles (lane = quad*16+l16)
    float vmax = st[0][0];
    #pragma unroll
    for (int nt = 0; nt < 4; ++nt)
        #pragma unroll
        for (int reg = 0; reg < 4; ++reg)
            vmax = fmaxf(vmax, st[nt][reg]);
    vmax = fmaxf(vmax, __shfl_xor(vmax, 16, 64));
    vmax = fmaxf(vmax, __shfl_xor(vmax, 32, 64));

    const float mnew = fmaxf(m_i, vmax);
    const float alpha = __builtin_amdgcn_exp2f(m_i - mnew);
    m_i = mnew;

    float vsum = 0.f;
    #pragma unroll
    for (int nt = 0; nt < 4; ++nt)
        #pragma unroll
        for (int reg = 0; reg < 4; ++reg) {
            const float p = __builtin_amdgcn_exp2f(st[nt][reg] - mnew);
            st[nt][reg] = p;
            vsum += p;
        }
    vsum += __shfl_xor(vsum, 16, 64);
    vsum += __shfl_xor(vsum, 32, 64);
    l_i = l_i * alpha + vsum;

    #pragma unroll
    for (int dt = 0; dt < 4; ++dt)
        #pragma unroll
        for (int reg = 0; reg < 4; ++reg)
            Oacc[dt][reg] *= alpha;

    // P^T B-operand: reg j<4 = st[2p][j] (key p*32+quad*4+j),
    //                reg j>=4 = st[2p+1][j-4] (key p*32+16+quad*4+j-4)
    #pragma unroll
    for (int pair = 0; pair < 2; ++pair) {
        u16 pa[8];
        #pragma unroll
        for (int j = 0; j < 4; ++j) {
            pa[j]     = f2bf(st[2 * pair][j]);
            pa[4 + j] = f2bf(st[2 * pair + 1][j]);
        }
        const bf16x8 pb = *(const bf16x8*)pa;
        #pragma unroll
        for (int dt = 0; dt < 4; ++dt)
            Oacc[dt] = mfma16(fv[pair][dt], pb, Oacc[dt]);
    }
}

__global__ __launch_bounds__(256, 2)
void attn_kernel(const u16* __restrict__ Q, const u16* __restrict__ Kb,
                 const u16* __restrict__ Vt, u16* __restrict__ O) {
    __shared__ alignas(16) u16 Ks[2][64 * KST];
    __shared__ alignas(16) u16 Vs[2][64 * KST];

    const int p = blockIdx.x;         // 0..15
    const int bh = blockIdx.y;
    const int qtA = 31 - p;           // big tile; also jmax
    const int qtB = p;                // small tile
    const int jmax = qtA;

    const int tid = threadIdx.x;
    const int wave = tid >> 6, lane = tid & 63;
    const int quad = lane >> 4, l16 = lane & 15;

    const u16* Qh = Q  + (size_t)bh * TT * DH;
    const u16* Kh = Kb + (size_t)bh * TT * DH;
    const u16* Vh = Vt + (size_t)bh * DH * TT;

    const int rowA = qtA * 64 + wave * 16;
    const int rowB = qtB * 64 + wave * 16;

    // Q fragments (B-operand: n = l16 = q, k = quad*8+j over d)
    bf16x8 fqA[2], fqB[2];
    fqA[0] = *(const bf16x8*)&Qh[(rowA + l16) * DH + quad * 8];
    fqA[1] = *(const bf16x8*)&Qh[(rowA + l16) * DH + 32 + quad * 8];
    fqB[0] = *(const bf16x8*)&Qh[(rowB + l16) * DH + quad * 8];
    fqB[1] = *(const bf16x8*)&Qh[(rowB + l16) * DH + 32 + quad * 8];

    f32x4 OA[4] = {}, OB[4] = {};
    float mA = -INFINITY, lA = 0.f, mB = -INFINITY, lB = 0.f;

    // Chunk staging: thread i covers 16B at row (i>>3), col (i&7)*8, +row32.
    const int trow = tid >> 3;
    const int ic   = tid & 7;            // 8-key group index
    const int tcol = ic * 8;
    // V pair-permuted destination column for this thread's 8 keys:
    //   keys 8*ic..8*ic+7 -> cols c1..c1+3 and c1+8..c1+11
    const int vc1 = 32 * (ic >> 2) + 16 * (ic & 1) + 4 * ((ic & 3) >> 1);
    uint4 kr0, kr1, vr0, vr1;

    auto load_chunk = [&](int j) {
        const u16* ks = Kh + (size_t)j * 64 * DH;
        kr0 = *(const uint4*)&ks[trow * DH + tcol];
        kr1 = *(const uint4*)&ks[(trow + 32) * DH + tcol];
        const u16* vs = Vh + (size_t)j * 64;
        vr0 = *(const uint4*)&vs[(size_t)trow * TT + tcol];
        vr1 = *(const uint4*)&vs[(size_t)(trow + 32) * TT + tcol];
    };
    auto write_chunk = [&](int buf) {
        *(uint4*)&Ks[buf][trow * KST + tcol]        = kr0;
        *(uint4*)&Ks[buf][(trow + 32) * KST + tcol] = kr1;
        // V: split each 16B into two 8B halves at permuted columns
        *(uint2*)&Vs[buf][trow * KST + vc1]            = *(const uint2*)&vr0;
        *(uint2*)&Vs[buf][trow * KST + vc1 + 8]        = *((const uint2*)&vr0 + 1);
        *(uint2*)&Vs[buf][(trow + 32) * KST + vc1]     = *(const uint2*)&vr1;
        *(uint2*)&Vs[buf][(trow + 32) * KST + vc1 + 8] = *((const uint2*)&vr1 + 1);
    };

    load_chunk(0);
    write_chunk(0);

    for (int j = 0; j <= jmax; ++j) {
        const int cur = j & 1;
        __syncthreads();                    // buf[cur] staged & visible
        if (j < jmax) load_chunk(j + 1);    // loads fly during compute

        // Hoist K/V fragments once per chunk (shared by both q-tiles)
        bf16x8 fk[4][2], fv[2][4];
        #pragma unroll
        for (int nt = 0; nt < 4; ++nt) {
            fk[nt][0] = *(const bf16x8*)&Ks[cur][(nt * 16 + l16) * KST + quad * 8];
            fk[nt][1] = *(const bf16x8*)&Ks[cur][(nt * 16 + l16) * KST + 32 + quad * 8];
        }
        #pragma unroll
        for (int pair = 0; pair < 2; ++pair)
            #pragma unroll
            for (int dt = 0; dt < 4; ++dt)
                fv[pair][dt] = *(const bf16x8*)
                    &Vs[cur][(dt * 16 + l16) * KST + pair * 32 + quad * 8];

        attn_step(fk, fv, fqA, OA, mA, lA, (j == qtA), wave, quad, l16);
        if (j <= qtB)
            attn_step(fk, fv, fqB, OB, mB, lB, (j == qtB), wave, quad, l16);
        if (j < jmax) write_chunk(cur ^ 1); // after all buf[cur^1] readers done
    }

    // Epilogue: O^T rows d = dt*16+quad*4+reg, col q = l16; write (B,T,C).
    const int b = bh >> 4, h = bh & 15;
    const float rA = 1.f / lA, rB = 1.f / lB;
    #pragma unroll
    for (int dt = 0; dt < 4; ++dt) {
        u16 oa[4], ob[4];
        #pragma unroll
        for (int reg = 0; reg < 4; ++reg) {
            oa[reg] = f2bf(OA[dt][reg] * rA);
            ob[reg] = f2bf(OB[dt][reg] * rB);
        }
        *(uint2*)&O[((size_t)(b * TT + rowA + l16)) * CD + h * DH + dt * 16 + quad * 4] =
            *(const uint2*)oa;
        *(uint2*)&O[((size_t)(b * TT + rowB + l16)) * CD + h * DH + dt * 16 + quad * 4] =
            *(const uint2*)ob;
    }
}

// ---------------------------------------------------------------------------
extern "C" void kernel_launch(void* const* d_in, const int* in_sizes, int n_in,
                              void* d_out, int out_size, void* d_ws, size_t ws_size,
                              hipStream_t stream) {
    (void)in_sizes; (void)n_in; (void)out_size; (void)ws_size;
    const float* x    = (const float*)d_in[0];   // (4096, 1024) fp32
    const float* Wqkv = (const float*)d_in[1];   // (1024, 3072) fp32
    const float* Wo   = (const float*)d_in[2];   // (1024, 1024) fp32
    float* out = (float*)d_out;                  // (4096, 1024) fp32

    char* ws = (char*)d_ws;
    u16* xb    = (u16*)(ws + 0);                    // 4096x1024  (8 MB)
    u16* WqkvT = (u16*)(ws + (8u  << 20));          // 3072x1024  (6 MB)
    u16* WoT   = (u16*)(ws + (14u << 20));          // 1024x1024  (2 MB)
    u16* Qb    = (u16*)(ws + (16u << 20));          // (B,H,T,64) (8 MB)
    u16* Kb    = (u16*)(ws + (24u << 20));          // (B,H,T,64) (8 MB)
    u16* Vt    = (u16*)(ws + (32u << 20));          // (B,H,64,T) (8 MB)
    u16* attn  = (u16*)(ws + (40u << 20));          // (B,T,C)    (8 MB)

    prep_kernel<<<6144, 256, 0, stream>>>(x, xb, Wqkv, WqkvT, Wo, WoT);

    // qkv = x @ W_qkv, scattered to Q (pre-scaled) / K (B,H,T,64), V^T (B,H,64,T)
    gemm_bt<1, 128><<<dim3(3072 / 128, BT / 128), 256, 0, stream>>>(
        xb, WqkvT, Qb, Kb, Vt, nullptr, BT, 3072, CD);

    attn_kernel<<<dim3(16, BB * HH), 256, 0, stream>>>(Qb, Kb, Vt, attn);

    // out = attn @ W_o  (fp32 store to d_out); BN=64 -> 512 blocks = 2/CU
    gemm_bt<0, 64><<<dim3(CD / 64, BT / 128), 256, 0, stream>>>(
        attn, WoT, nullptr, nullptr, nullptr, out, BT, CD, CD);
}